// Round 6
// baseline (169.157 us; speedup 1.0000x reference)
//
#include <hip/hip_runtime.h>

#define WIRES   12
#define NSTATE  4096          // 2^12
#define QDEPTH  8
#define BLOCK   64            // ONE wave per block = one batch element
#define PER_T   64            // 6 local index bits; state in 128 VGPRs

using f2 = __attribute__((ext_vector_type(2))) float;

// Padded LDS layout: element i (0..4095) lives at f2-slot i + (i>>6)
// (row pitch 65). Structured row/col patterns are conflict-free and their
// addresses are base + compile-time immediate.
__device__ __forceinline__ int pad(int i) { return i + (i >> 6); }

// Column j of the GF(2)-linear CNOT-ring permutation of layer l:
// F = g_0∘g_1∘...∘g_11 (g_11 applied first / innermost).
constexpr int colF(int l, int j) {
    int rr = (l % (WIRES - 1)) + 1;
    int v = 1 << j;
    for (int k = WIRES - 1; k >= 0; --k) {
        int bc = 11 - k;                   // control bit
        int bt = 11 - ((k + rr) % WIRES);  // target bit
        v ^= ((v >> bc) & 1) << bt;
    }
    return v;
}
struct ColsT { int v[QDEPTH][WIRES]; };
constexpr ColsT mkCols() {
    ColsT c{};
    for (int l = 0; l < QDEPTH; ++l)
        for (int j = 0; j < WIRES; ++j) c.v[l][j] = colF(l, j);
    return c;
}
static __device__ const ColsT COLS = mkCols();   // rodata, uniform s_load

// 2x2 complex gate on local register bit P (compile-time => static reg idx).
// Explicit llvm.fma.v2f32 chains so the backend emits v_pk_fma_f32; the
// perp {-y,x} is a shuffle+neg foldable into VOP3P op_sel/neg modifiers.
// out0 = u00*s0 + u01*s1 ; out1 = u10*s0 + u11*s1 (complex)
//   u*s = u.re*(x,y) + u.im*(-y,x)
template<int P>
__device__ __forceinline__ void gate(f2 r[PER_T], const f2* __restrict__ m)
{
    const f2 u00 = m[0], u01 = m[1], u10 = m[2], u11 = m[3];
    #pragma unroll
    for (int pr = 0; pr < PER_T / 2; ++pr) {
        const int k0 = ((pr >> P) << (P + 1)) | (pr & ((1 << P) - 1));
        const int k1 = k0 | (1 << P);
        const f2 s0 = r[k0], s1 = r[k1];
        const f2 t0 = f2{-s0.y, s0.x};   // i * s0
        const f2 t1 = f2{-s1.y, s1.x};   // i * s1
        f2 a = s0 * u00.x;                                           // pk_mul
        a = __builtin_elementwise_fma(t0, f2{u00.y, u00.y}, a);
        a = __builtin_elementwise_fma(s1, f2{u01.x, u01.x}, a);
        a = __builtin_elementwise_fma(t1, f2{u01.y, u01.y}, a);
        f2 b = s0 * u10.x;
        b = __builtin_elementwise_fma(t0, f2{u10.y, u10.y}, b);
        b = __builtin_elementwise_fma(s1, f2{u11.x, u11.x}, b);
        b = __builtin_elementwise_fma(t1, f2{u11.y, u11.y}, b);
        r[k0] = a;
        r[k1] = b;
    }
}

// One wave = one batch element. State: r[k] = amp[(lane<<6)|k] (canonical).
// Per layer: 6 gates in regs (wires 6..11) -> LDS transpose -> 6 gates
// (wires 0..5) -> LDS gather folding the CNOT permutation F back to
// canonical. NO __syncthreads anywhere: single-wave blocks, compiler
// lgkmcnt ordering handles all LDS dependencies.
__global__ __launch_bounds__(BLOCK, 2) void qsim_kernel(
    const float* __restrict__ x,
    const float* __restrict__ wts,
    const int*   __restrict__ reps_ptr,
    float*       __restrict__ out,
    int write_mode)
{
    __shared__ f2 st[65 * 64];                           // 33280 B
    __shared__ __align__(16) f2 mats[QDEPTH * WIRES][4]; // 3 KB

    const int lane = threadIdx.x;
    const int b    = blockIdx.x;

    // ---- rotation matrices from tanh(weights) (96 mats, 64 lanes: loop) ----
    for (int t = lane; t < QDEPTH * WIRES; t += BLOCK) {
        float phi   = tanhf(wts[t * 3 + 0]);
        float theta = tanhf(wts[t * 3 + 1]);
        float omega = tanhf(wts[t * 3 + 2]);
        float c  = cosf(theta * 0.5f);
        float s  = sinf(theta * 0.5f);
        float a  = 0.5f * (phi + omega);
        float bm = 0.5f * (phi - omega);
        float ca = cosf(a),  sa = sinf(a);
        float cb = cosf(bm), sb = sinf(bm);
        mats[t][0] = f2{ c * ca, -c * sa};   // U00 = e^{-ia} c
        mats[t][1] = f2{-s * cb, -s * sb};   // U01 = -conj(em) s
        mats[t][2] = f2{ s * cb, -s * sb};   // U10 = em s
        mats[t][3] = f2{ c * ca,  c * sa};   // U11 = conj(ep) c
    }

    // ---- coalesced load of x, staged via LDS as packed real pairs ----
    const float4* xb4 = (const float4*)(x + (size_t)b * NSTATE);
    #pragma unroll
    for (int c = 0; c < 16; ++c) {
        int g = c * BLOCK + lane;            // coalesced float4 index
        float4 v = xb4[g];
        st[pad(2 * g)]     = f2{v.x, v.y};   // pair p = amps(2p,2p+1) reals
        st[pad(2 * g + 1)] = f2{v.z, v.w};
    }
    f2 r[PER_T];
    #pragma unroll
    for (int m = 0; m < 32; ++m) {
        f2 pr2 = st[pad((lane << 5) | m)];
        r[2*m]   = f2{pr2.x, 0.f};
        r[2*m+1] = f2{pr2.y, 0.f};
    }

    const int reps = reps_ptr[0];
    for (int rep = 0; rep < reps; ++rep) {
        #pragma unroll 1
        for (int l = 0; l < QDEPTH; ++l) {
            const f2* M = &mats[l * WIRES][0];

            // Phase A: wires 6..11 on local bits 5..0 (bit = 11-wire)
            gate<5>(r, M + 6*4);  gate<4>(r, M + 7*4);
            gate<3>(r, M + 8*4);  gate<2>(r, M + 9*4);
            gate<1>(r, M + 10*4); gate<0>(r, M + 11*4);

            // RT1: canonical -> hi-bits-local (addresses = base + imm)
            #pragma unroll
            for (int k = 0; k < PER_T; ++k) st[65 * lane + k] = r[k];
            #pragma unroll
            for (int k = 0; k < PER_T; ++k) r[k] = st[65 * k + lane];
            // now r[k] = amp[(k<<6)|lane]

            // Phase B: wires 0..5 on local bits 5..0 (local bit = 5-wire)
            gate<5>(r, M + 0*4); gate<4>(r, M + 1*4);
            gate<3>(r, M + 2*4); gate<2>(r, M + 3*4);
            gate<1>(r, M + 4*4); gate<0>(r, M + 5*4);

            // RT2: store hi-local, gather canonical ∘ F (CNOT ring)
            #pragma unroll
            for (int k = 0; k < PER_T; ++k) st[65 * k + lane] = r[k];

            const int c0 = COLS.v[l][0], c1 = COLS.v[l][1], c2 = COLS.v[l][2];
            const int c3 = COLS.v[l][3], c4 = COLS.v[l][4], c5 = COLS.v[l][5];
            int Ft = 0;
            #pragma unroll
            for (int j = 0; j < 6; ++j)
                Ft ^= ((lane >> j) & 1) ? COLS.v[l][6 + j] : 0;
            #pragma unroll
            for (int k = 0; k < PER_T; ++k) {
                int ck = ((k & 1)  ? c0 : 0) ^ ((k & 2)  ? c1 : 0) ^
                         ((k & 4)  ? c2 : 0) ^ ((k & 8)  ? c3 : 0) ^
                         ((k & 16) ? c4 : 0) ^ ((k & 32) ? c5 : 0);
                r[k] = st[pad(Ft ^ ck)];
            }
            // r[k] = amp_after_layer[(lane<<6)|k]  (canonical again)
        }
    }

    // ---- write out ----
    if (write_mode == 0) {
        // harness views complex output as float32 real part
        #pragma unroll
        for (int m = 0; m < 32; ++m)
            st[pad((lane << 5) | m)] = f2{r[2*m].x, r[2*m+1].x};
        float4* ob4 = (float4*)(out + (size_t)b * NSTATE);
        #pragma unroll
        for (int c = 0; c < 16; ++c) {
            int g = c * BLOCK + lane;
            f2 a  = st[pad(2 * g)];
            f2 b2 = st[pad(2 * g + 1)];
            ob4[g] = make_float4(a.x, a.y, b2.x, b2.y);
        }
    } else {
        float2* ob = (float2*)out + (size_t)b * NSTATE;
        #pragma unroll
        for (int k = 0; k < PER_T; ++k)
            ob[(lane << 6) | k] = make_float2(r[k].x, r[k].y);
    }
}

extern "C" void kernel_launch(void* const* d_in, const int* in_sizes, int n_in,
                              void* d_out, int out_size, void* d_ws, size_t ws_size,
                              hipStream_t stream) {
    const float* x    = (const float*)d_in[0];
    const float* wts  = (const float*)d_in[1];
    const int*   reps = (const int*)d_in[2];
    float*       out  = (float*)d_out;
    (void)in_sizes; (void)n_in; (void)d_ws; (void)ws_size;

    const int write_mode = (out_size >= 2 * 1024 * NSTATE) ? 1 : 0;

    qsim_kernel<<<1024, BLOCK, 0, stream>>>(x, wts, reps, out, write_mode);
}

// Round 7
// 156.014 us; speedup vs baseline: 1.0842x; 1.0842x over previous
//
#include <hip/hip_runtime.h>

#define WIRES   12
#define NSTATE  4096          // 2^12
#define QDEPTH  8
#define BLOCK   64            // ONE wave per block = one batch element
#define PER_T   64            // 6 local index bits; state in 128 VGPRs

using f2 = __attribute__((ext_vector_type(2))) float;

// Padded LDS layout: element i (0..4095) lives at f2-slot i + (i>>6)
// (row pitch 65). Structured row/col patterns are conflict-light and their
// addresses are base + compile-time immediate.
__device__ __forceinline__ int pad(int i) { return i + (i >> 6); }

// Column j of the GF(2)-linear CNOT-ring permutation of layer l:
// F = g_0∘g_1∘...∘g_11 (g_11 applied first / innermost).
constexpr int colF(int l, int j) {
    int rr = (l % (WIRES - 1)) + 1;
    int v = 1 << j;
    for (int k = WIRES - 1; k >= 0; --k) {
        int bc = 11 - k;                   // control bit
        int bt = 11 - ((k + rr) % WIRES);  // target bit
        v ^= ((v >> bc) & 1) << bt;
    }
    return v;
}
struct ColsT { int v[QDEPTH][WIRES]; };
constexpr ColsT mkCols() {
    ColsT c{};
    for (int l = 0; l < QDEPTH; ++l)
        for (int j = 0; j < WIRES; ++j) c.v[l][j] = colF(l, j);
    return c;
}
static __device__ const ColsT COLS = mkCols();   // rodata, uniform s_load

// 2x2 complex gate on local register bit P, forced VOP3P packed math.
// Gate entries pre-expanded: urr = {re,re}, uw = {-im,+im}.
//   u*s = pk_mul(s,urr) then pk_fma(swap(s), uw) via op_sel[src0]:
//   lo = s.hi*uw.lo + acc.lo = -im*y ; hi = s.lo*uw.hi + acc.hi = +im*x
template<int P>
__device__ __forceinline__ void gate(f2 r[PER_T], const f2* __restrict__ m)
{
    const f2 u00r = m[0], u00w = m[1], u01r = m[2], u01w = m[3];
    const f2 u10r = m[4], u10w = m[5], u11r = m[6], u11w = m[7];
    #pragma unroll
    for (int pr = 0; pr < PER_T / 2; ++pr) {
        const int k0 = ((pr >> P) << (P + 1)) | (pr & ((1 << P) - 1));
        const int k1 = k0 | (1 << P);
        const f2 s0 = r[k0], s1 = r[k1];
        f2 a, b;
        asm("v_pk_mul_f32 %0, %1, %2" : "=v"(a) : "v"(s0), "v"(u00r));
        asm("v_pk_fma_f32 %0, %1, %2, %0 op_sel:[1,0,0] op_sel_hi:[0,1,1]"
            : "+v"(a) : "v"(s0), "v"(u00w));
        asm("v_pk_fma_f32 %0, %1, %2, %0" : "+v"(a) : "v"(s1), "v"(u01r));
        asm("v_pk_fma_f32 %0, %1, %2, %0 op_sel:[1,0,0] op_sel_hi:[0,1,1]"
            : "+v"(a) : "v"(s1), "v"(u01w));
        asm("v_pk_mul_f32 %0, %1, %2" : "=v"(b) : "v"(s0), "v"(u10r));
        asm("v_pk_fma_f32 %0, %1, %2, %0 op_sel:[1,0,0] op_sel_hi:[0,1,1]"
            : "+v"(b) : "v"(s0), "v"(u10w));
        asm("v_pk_fma_f32 %0, %1, %2, %0" : "+v"(b) : "v"(s1), "v"(u11r));
        asm("v_pk_fma_f32 %0, %1, %2, %0 op_sel:[1,0,0] op_sel_hi:[0,1,1]"
            : "+v"(b) : "v"(s1), "v"(u11w));
        r[k0] = a;
        r[k1] = b;
    }
}

// One wave = one batch element. State: r[k] = amp[(lane<<6)|k] (canonical).
// Per layer: 6 gates in regs (wires 6..11) -> LDS transpose -> 6 gates
// (wires 0..5) -> LDS gather folding the CNOT permutation F back to
// canonical. NO __syncthreads: single-wave blocks, lgkmcnt ordering only.
__global__ __launch_bounds__(BLOCK, 2) void qsim_kernel(
    const float* __restrict__ x,
    const float* __restrict__ wts,
    const int*   __restrict__ reps_ptr,
    float*       __restrict__ out,
    int write_mode)
{
    __shared__ f2 st[65 * 64];                           // 33280 B
    __shared__ __align__(16) f2 mats[QDEPTH * WIRES][8]; // 6 KB

    const int lane = threadIdx.x;
    const int b    = blockIdx.x;

    // ---- rotation matrices from tanh(weights) (96 mats, 64 lanes: loop) ----
    for (int t = lane; t < QDEPTH * WIRES; t += BLOCK) {
        float phi   = tanhf(wts[t * 3 + 0]);
        float theta = tanhf(wts[t * 3 + 1]);
        float omega = tanhf(wts[t * 3 + 2]);
        float c  = cosf(theta * 0.5f);
        float s  = sinf(theta * 0.5f);
        float a  = 0.5f * (phi + omega);
        float bm = 0.5f * (phi - omega);
        float ca = cosf(a),  sa = sinf(a);
        float cb = cosf(bm), sb = sinf(bm);
        // U00 = (c*ca, -c*sa)  U01 = (-s*cb, -s*sb)
        // U10 = (s*cb, -s*sb)  U11 = (c*ca,  c*sa)
        mats[t][0] = f2{ c * ca,  c * ca};   // u00 re,re
        mats[t][1] = f2{ c * sa, -c * sa};   // {-im,+im}, im=-c*sa
        mats[t][2] = f2{-s * cb, -s * cb};   // u01 re,re
        mats[t][3] = f2{ s * sb, -s * sb};   // {-im,+im}, im=-s*sb
        mats[t][4] = f2{ s * cb,  s * cb};   // u10 re,re
        mats[t][5] = f2{ s * sb, -s * sb};   // {-im,+im}, im=-s*sb
        mats[t][6] = f2{ c * ca,  c * ca};   // u11 re,re
        mats[t][7] = f2{-c * sa,  c * sa};   // {-im,+im}, im=+c*sa
    }

    // ---- coalesced load of x, staged via LDS as packed real pairs ----
    const float4* xb4 = (const float4*)(x + (size_t)b * NSTATE);
    #pragma unroll
    for (int c = 0; c < 16; ++c) {
        int g = c * BLOCK + lane;            // coalesced float4 index
        float4 v = xb4[g];
        st[pad(2 * g)]     = f2{v.x, v.y};   // pair p = amps(2p,2p+1) reals
        st[pad(2 * g + 1)] = f2{v.z, v.w};
    }
    f2 r[PER_T];
    #pragma unroll
    for (int m = 0; m < 32; ++m) {
        f2 pr2 = st[pad((lane << 5) | m)];
        r[2*m]   = f2{pr2.x, 0.f};
        r[2*m+1] = f2{pr2.y, 0.f};
    }

    const int reps = reps_ptr[0];
    for (int rep = 0; rep < reps; ++rep) {
        #pragma unroll 1
        for (int l = 0; l < QDEPTH; ++l) {
            const f2* M = &mats[l * WIRES][0];

            // Phase A: wires 6..11 on local bits 5..0 (bit = 11-wire)
            gate<5>(r, M + 6*8);  gate<4>(r, M + 7*8);
            gate<3>(r, M + 8*8);  gate<2>(r, M + 9*8);
            gate<1>(r, M + 10*8); gate<0>(r, M + 11*8);

            // RT1: canonical -> hi-bits-local (addresses = base + imm)
            #pragma unroll
            for (int k = 0; k < PER_T; ++k) st[65 * lane + k] = r[k];
            #pragma unroll
            for (int k = 0; k < PER_T; ++k) r[k] = st[65 * k + lane];
            // now r[k] = amp[(k<<6)|lane]

            // Phase B: wires 0..5 on local bits 5..0 (local bit = 5-wire)
            gate<5>(r, M + 0*8); gate<4>(r, M + 1*8);
            gate<3>(r, M + 2*8); gate<2>(r, M + 3*8);
            gate<1>(r, M + 4*8); gate<0>(r, M + 5*8);

            // RT2: store hi-local, gather canonical ∘ F (CNOT ring)
            #pragma unroll
            for (int k = 0; k < PER_T; ++k) st[65 * k + lane] = r[k];

            const int c0 = COLS.v[l][0], c1 = COLS.v[l][1], c2 = COLS.v[l][2];
            const int c3 = COLS.v[l][3], c4 = COLS.v[l][4], c5 = COLS.v[l][5];
            int Ft = 0;
            #pragma unroll
            for (int j = 0; j < 6; ++j)
                Ft ^= ((lane >> j) & 1) ? COLS.v[l][6 + j] : 0;
            #pragma unroll
            for (int k = 0; k < PER_T; ++k) {
                int ck = ((k & 1)  ? c0 : 0) ^ ((k & 2)  ? c1 : 0) ^
                         ((k & 4)  ? c2 : 0) ^ ((k & 8)  ? c3 : 0) ^
                         ((k & 16) ? c4 : 0) ^ ((k & 32) ? c5 : 0);
                r[k] = st[pad(Ft ^ ck)];
            }
            // r[k] = amp_after_layer[(lane<<6)|k]  (canonical again)
        }
    }

    // ---- write out ----
    if (write_mode == 0) {
        // harness views complex output as float32 real part
        #pragma unroll
        for (int m = 0; m < 32; ++m)
            st[pad((lane << 5) | m)] = f2{r[2*m].x, r[2*m+1].x};
        float4* ob4 = (float4*)(out + (size_t)b * NSTATE);
        #pragma unroll
        for (int c = 0; c < 16; ++c) {
            int g = c * BLOCK + lane;
            f2 a  = st[pad(2 * g)];
            f2 b2 = st[pad(2 * g + 1)];
            ob4[g] = make_float4(a.x, a.y, b2.x, b2.y);
        }
    } else {
        float2* ob = (float2*)out + (size_t)b * NSTATE;
        #pragma unroll
        for (int k = 0; k < PER_T; ++k)
            ob[(lane << 6) | k] = make_float2(r[k].x, r[k].y);
    }
}

extern "C" void kernel_launch(void* const* d_in, const int* in_sizes, int n_in,
                              void* d_out, int out_size, void* d_ws, size_t ws_size,
                              hipStream_t stream) {
    const float* x    = (const float*)d_in[0];
    const float* wts  = (const float*)d_in[1];
    const int*   reps = (const int*)d_in[2];
    float*       out  = (float*)d_out;
    (void)in_sizes; (void)n_in; (void)d_ws; (void)ws_size;

    const int write_mode = (out_size >= 2 * 1024 * NSTATE) ? 1 : 0;

    qsim_kernel<<<1024, BLOCK, 0, stream>>>(x, wts, reps, out, write_mode);
}

// Round 8
// 154.840 us; speedup vs baseline: 1.0925x; 1.0076x over previous
//
#include <hip/hip_runtime.h>

#define WIRES   12
#define NSTATE  4096          // 2^12
#define QDEPTH  8
#define BLOCK   64            // ONE wave per block = one batch element
#define PER_T   64            // 6 local index bits; state in 128 VGPRs

using f2 = __attribute__((ext_vector_type(2))) float;

// Padded LDS layout: element i (0..4095) lives at f2-slot i + (i>>6)
// (row pitch 65). Structured patterns conflict-light; addresses are
// base + compile-time immediate.
__device__ __forceinline__ int pad(int i) { return i + (i >> 6); }

// Column j of the GF(2)-linear CNOT-ring permutation of layer l:
// F = g_0∘g_1∘...∘g_11 (g_11 applied first / innermost).
constexpr int colF(int l, int j) {
    int rr = (l % (WIRES - 1)) + 1;
    int v = 1 << j;
    for (int k = WIRES - 1; k >= 0; --k) {
        int bc = 11 - k;                   // control bit
        int bt = 11 - ((k + rr) % WIRES);  // target bit
        v ^= ((v >> bc) & 1) << bt;
    }
    return v;
}
struct ColsT { int v[QDEPTH][WIRES]; };
constexpr ColsT mkCols() {
    ColsT c{};
    for (int l = 0; l < QDEPTH; ++l)
        for (int j = 0; j < WIRES; ++j) c.v[l][j] = colF(l, j);
    return c;
}
static __device__ const ColsT COLS = mkCols();   // rodata, uniform s_load

// ---- setup kernel: 96 rotation matrices -> d_ws (8 f2 per gate) ----
// Entries pre-expanded for packed math: urr = {re,re}, uw = {-im,+im}.
__global__ void mats_kernel(const float* __restrict__ wts, f2* __restrict__ mg)
{
    int t = blockIdx.x * blockDim.x + threadIdx.x;
    if (t >= QDEPTH * WIRES) return;
    float phi   = tanhf(wts[t * 3 + 0]);
    float theta = tanhf(wts[t * 3 + 1]);
    float omega = tanhf(wts[t * 3 + 2]);
    float c  = cosf(theta * 0.5f);
    float s  = sinf(theta * 0.5f);
    float a  = 0.5f * (phi + omega);
    float bm = 0.5f * (phi - omega);
    float ca = cosf(a),  sa = sinf(a);
    float cb = cosf(bm), sb = sinf(bm);
    // U00 = (c*ca, -c*sa)  U01 = (-s*cb, -s*sb)
    // U10 = (s*cb, -s*sb)  U11 = (c*ca,  c*sa)
    f2* m = mg + t * 8;
    m[0] = f2{ c * ca,  c * ca};   // u00 re,re
    m[1] = f2{ c * sa, -c * sa};   // {-im,+im}, im=-c*sa
    m[2] = f2{-s * cb, -s * cb};   // u01 re,re
    m[3] = f2{ s * sb, -s * sb};   // {-im,+im}, im=-s*sb
    m[4] = f2{ s * cb,  s * cb};   // u10 re,re
    m[5] = f2{ s * sb, -s * sb};   // {-im,+im}, im=-s*sb
    m[6] = f2{ c * ca,  c * ca};   // u11 re,re
    m[7] = f2{-c * sa,  c * sa};   // {-im,+im}, im=+c*sa
}

// 2x2 complex gate on local register bit P. ONE asm block per TWO pairs:
// four accumulator chains (a0,b0,a1,b1) issued round-robin so dependent
// pk-ops are 4 instructions (8 issue cycles) apart -> no latency stalls
// even at 1 wave/SIMD in-order issue. Perp {-y,x} folded via op_sel.
template<int P>
__device__ __forceinline__ void gate(f2 r[PER_T], const f2* __restrict__ m)
{
    const f2 u00r = m[0], u00w = m[1], u01r = m[2], u01w = m[3];
    const f2 u10r = m[4], u10w = m[5], u11r = m[6], u11w = m[7];
    #pragma unroll
    for (int pr = 0; pr < PER_T / 2; pr += 2) {
        const int k0 = ((pr >> P) << (P + 1)) | (pr & ((1 << P) - 1));
        const int k1 = k0 | (1 << P);
        const int q  = pr + 1;
        const int j0 = ((q >> P) << (P + 1)) | (q & ((1 << P) - 1));
        const int j1 = j0 | (1 << P);
        f2 a0, b0, a1, b1;
        asm("v_pk_mul_f32 %0, %4, %8\n\t"
            "v_pk_mul_f32 %1, %4, %12\n\t"
            "v_pk_mul_f32 %2, %6, %8\n\t"
            "v_pk_mul_f32 %3, %6, %12\n\t"
            "v_pk_fma_f32 %0, %4, %9, %0 op_sel:[1,0,0] op_sel_hi:[0,1,1]\n\t"
            "v_pk_fma_f32 %1, %4, %13, %1 op_sel:[1,0,0] op_sel_hi:[0,1,1]\n\t"
            "v_pk_fma_f32 %2, %6, %9, %2 op_sel:[1,0,0] op_sel_hi:[0,1,1]\n\t"
            "v_pk_fma_f32 %3, %6, %13, %3 op_sel:[1,0,0] op_sel_hi:[0,1,1]\n\t"
            "v_pk_fma_f32 %0, %5, %10, %0\n\t"
            "v_pk_fma_f32 %1, %5, %14, %1\n\t"
            "v_pk_fma_f32 %2, %7, %10, %2\n\t"
            "v_pk_fma_f32 %3, %7, %14, %3\n\t"
            "v_pk_fma_f32 %0, %5, %11, %0 op_sel:[1,0,0] op_sel_hi:[0,1,1]\n\t"
            "v_pk_fma_f32 %1, %5, %15, %1 op_sel:[1,0,0] op_sel_hi:[0,1,1]\n\t"
            "v_pk_fma_f32 %2, %7, %11, %2 op_sel:[1,0,0] op_sel_hi:[0,1,1]\n\t"
            "v_pk_fma_f32 %3, %7, %15, %3 op_sel:[1,0,0] op_sel_hi:[0,1,1]"
            : "=&v"(a0), "=&v"(b0), "=&v"(a1), "=&v"(b1)
            : "v"(r[k0]), "v"(r[k1]), "v"(r[j0]), "v"(r[j1]),
              "v"(u00r), "v"(u00w), "v"(u01r), "v"(u01w),
              "v"(u10r), "v"(u10w), "v"(u11r), "v"(u11w));
        r[k0] = a0; r[k1] = b0; r[j0] = a1; r[j1] = b1;
    }
}

// One wave = one batch element. State: r[k] = amp[(lane<<6)|k] (canonical).
// Per layer: 6 gates in regs (wires 6..11) -> LDS transpose -> 6 gates
// (wires 0..5) -> LDS gather folding the CNOT permutation F back to
// canonical. NO __syncthreads: single-wave blocks, lgkmcnt ordering only.
// launch_bounds(64,1): occupancy is grid-limited (1024 waves = 1/SIMD,
// LDS caps 4 blocks/CU) -> give the allocator full VGPR headroom.
__global__ __launch_bounds__(BLOCK, 1) void qsim_kernel(
    const float* __restrict__ x,
    const f2*    __restrict__ mats_g,
    const int*   __restrict__ reps_ptr,
    float*       __restrict__ out,
    int write_mode)
{
    __shared__ f2 st[65 * 64];                           // 33280 B

    const int lane = threadIdx.x;
    const int b    = blockIdx.x;

    // ---- coalesced load of x, staged via LDS as packed real pairs ----
    const float4* xb4 = (const float4*)(x + (size_t)b * NSTATE);
    #pragma unroll
    for (int c = 0; c < 16; ++c) {
        int g = c * BLOCK + lane;            // coalesced float4 index
        float4 v = xb4[g];
        st[pad(2 * g)]     = f2{v.x, v.y};   // pair p = amps(2p,2p+1) reals
        st[pad(2 * g + 1)] = f2{v.z, v.w};
    }
    f2 r[PER_T];
    #pragma unroll
    for (int m = 0; m < 32; ++m) {
        f2 pr2 = st[pad((lane << 5) | m)];
        r[2*m]   = f2{pr2.x, 0.f};
        r[2*m+1] = f2{pr2.y, 0.f};
    }

    const int reps = reps_ptr[0];
    for (int rep = 0; rep < reps; ++rep) {
        #pragma unroll 1
        for (int l = 0; l < QDEPTH; ++l) {
            const f2* M = mats_g + l * WIRES * 8;   // wave-uniform -> s_load

            // Phase A: wires 6..11 on local bits 5..0 (bit = 11-wire)
            gate<5>(r, M + 6*8);  gate<4>(r, M + 7*8);
            gate<3>(r, M + 8*8);  gate<2>(r, M + 9*8);
            gate<1>(r, M + 10*8); gate<0>(r, M + 11*8);

            // RT1: canonical -> hi-bits-local (addresses = base + imm)
            #pragma unroll
            for (int k = 0; k < PER_T; ++k) st[65 * lane + k] = r[k];
            #pragma unroll
            for (int k = 0; k < PER_T; ++k) r[k] = st[65 * k + lane];
            // now r[k] = amp[(k<<6)|lane]

            // Phase B: wires 0..5 on local bits 5..0 (local bit = 5-wire)
            gate<5>(r, M + 0*8); gate<4>(r, M + 1*8);
            gate<3>(r, M + 2*8); gate<2>(r, M + 3*8);
            gate<1>(r, M + 4*8); gate<0>(r, M + 5*8);

            // RT2: store hi-local, gather canonical ∘ F (CNOT ring)
            #pragma unroll
            for (int k = 0; k < PER_T; ++k) st[65 * k + lane] = r[k];

            const int c0 = COLS.v[l][0], c1 = COLS.v[l][1], c2 = COLS.v[l][2];
            const int c3 = COLS.v[l][3], c4 = COLS.v[l][4], c5 = COLS.v[l][5];
            int Ft = 0;
            #pragma unroll
            for (int j = 0; j < 6; ++j)
                Ft ^= ((lane >> j) & 1) ? COLS.v[l][6 + j] : 0;
            #pragma unroll
            for (int k = 0; k < PER_T; ++k) {
                int ck = ((k & 1)  ? c0 : 0) ^ ((k & 2)  ? c1 : 0) ^
                         ((k & 4)  ? c2 : 0) ^ ((k & 8)  ? c3 : 0) ^
                         ((k & 16) ? c4 : 0) ^ ((k & 32) ? c5 : 0);
                r[k] = st[pad(Ft ^ ck)];
            }
            // r[k] = amp_after_layer[(lane<<6)|k]  (canonical again)
        }
    }

    // ---- write out ----
    if (write_mode == 0) {
        // harness views complex output as float32 real part
        #pragma unroll
        for (int m = 0; m < 32; ++m)
            st[pad((lane << 5) | m)] = f2{r[2*m].x, r[2*m+1].x};
        float4* ob4 = (float4*)(out + (size_t)b * NSTATE);
        #pragma unroll
        for (int c = 0; c < 16; ++c) {
            int g = c * BLOCK + lane;
            f2 a  = st[pad(2 * g)];
            f2 b2 = st[pad(2 * g + 1)];
            ob4[g] = make_float4(a.x, a.y, b2.x, b2.y);
        }
    } else {
        float2* ob = (float2*)out + (size_t)b * NSTATE;
        #pragma unroll
        for (int k = 0; k < PER_T; ++k)
            ob[(lane << 6) | k] = make_float2(r[k].x, r[k].y);
    }
}

extern "C" void kernel_launch(void* const* d_in, const int* in_sizes, int n_in,
                              void* d_out, int out_size, void* d_ws, size_t ws_size,
                              hipStream_t stream) {
    const float* x    = (const float*)d_in[0];
    const float* wts  = (const float*)d_in[1];
    const int*   reps = (const int*)d_in[2];
    float*       out  = (float*)d_out;
    f2*          mg   = (f2*)d_ws;            // 96 gates * 8 f2 = 3 KB scratch
    (void)in_sizes; (void)n_in; (void)ws_size;

    const int write_mode = (out_size >= 2 * 1024 * NSTATE) ? 1 : 0;

    mats_kernel<<<1, 128, 0, stream>>>(wts, mg);
    qsim_kernel<<<1024, BLOCK, 0, stream>>>(x, mg, reps, out, write_mode);
}